// Round 10
// baseline (461.744 us; speedup 1.0000x reference)
//
#include <hip/hip_runtime.h>
#include <cstdint>
#include <cstddef>

#define N_NODES 1024
#define K_NEIGH 5
#define L_TIME  2016
#define PATCHSZ 12
#define EMBED   96
#define CINX    6
#define P_CNT   168
#define KDOT    72
#define OUT_PER_BN (EMBED * P_CNT)   // 16128

// d_ws layout (bytes): [0,20480) sampled ints; [24576,+18432) WH frags; then WL
#define WS_WH 24576
#define WS_WL (24576 + 18432)

typedef __attribute__((ext_vector_type(8))) short   bf16x8;
typedef __attribute__((ext_vector_type(4))) float   f32x4;
typedef __attribute__((ext_vector_type(4))) unsigned int u32x4;

// ---- bf16 split helpers (RNE) ----
__device__ __forceinline__ uint32_t f2bf_bits(float f) {
  uint32_t u = __float_as_uint(f);
  return (u + 0x7fffu + ((u >> 16) & 1u)) >> 16;
}
__device__ __forceinline__ float bf_hi_f(uint32_t hb) { return __uint_as_float(hb << 16); }

// ---------------- Threefry-2x32, JAX partitionable (validated) -------------
__device__ __forceinline__ uint32_t rotl32(uint32_t x, int r) {
  return (x << r) | (x >> (32 - r));
}
__device__ __forceinline__ uint32_t threefry_bits(uint32_t hi, uint32_t lo) {
  const uint32_t ks0 = 0u, ks1 = 42u;
  const uint32_t ks2 = ks0 ^ ks1 ^ 0x1BD11BDAu;
  uint32_t x0 = hi + ks0, x1 = lo + ks1;
#define TF_ROUND(r) { x0 += x1; x1 = rotl32(x1, (r)); x1 ^= x0; }
  TF_ROUND(13) TF_ROUND(15) TF_ROUND(26) TF_ROUND(6)
  x0 += ks1; x1 += ks2 + 1u;
  TF_ROUND(17) TF_ROUND(29) TF_ROUND(16) TF_ROUND(24)
  x0 += ks2; x1 += ks0 + 2u;
  TF_ROUND(13) TF_ROUND(15) TF_ROUND(26) TF_ROUND(6)
  x0 += ks0; x1 += ks1 + 3u;
  TF_ROUND(17) TF_ROUND(29) TF_ROUND(16) TF_ROUND(24)
  x0 += ks1; x1 += ks2 + 4u;
  TF_ROUND(13) TF_ROUND(15) TF_ROUND(26) TF_ROUND(6)
  x0 += ks2; x1 += ks0 + 5u;
#undef TF_ROUND
  return x0 ^ x1;
}
__device__ __forceinline__ float gumbel_from_bits(uint32_t bits) {
  float f = __uint_as_float((bits >> 9) | 0x3f800000u) - 1.0f;
  f = fmaxf(f, 1.17549435e-38f);
  return -logf(-logf(f));
}

// ---------------- Kernel 0: pre-pack W into A-frag hi/lo layout ------------
// Frag element (m,kc,L,j): w[o = m*16 + (L&15)][k = kc*32 + (L>>4)*8 + j],
// zero-padded for k>=72. Lane frag = 8 bf16 = 16 B contiguous.
__global__ __launch_bounds__(256)
void wpack_kernel(const float* __restrict__ wgt, char* __restrict__ ws) {
  const int tid = threadIdx.x;
  for (int t = tid; t < 1152; t += 256) {     // 18 (m*3+kc) x 64 lanes
    const int L  = t & 63;
    const int mk = t >> 6;
    const int kc = mk % 3;
    const int m  = mk / 3;
    const int o  = m * 16 + (L & 15);
    const int kbase = kc * 32 + (L >> 4) * 8;
    uint32_t hb[8], lb[8];
    #pragma unroll
    for (int j = 0; j < 8; ++j) {
      const int k = kbase + j;
      float v = (k < KDOT) ? wgt[o * KDOT + k] : 0.0f;
      hb[j] = f2bf_bits(v);
      lb[j] = f2bf_bits(v - bf_hi_f(hb[j]));
    }
    u32x4 ph, pl;
    #pragma unroll
    for (int i = 0; i < 4; ++i) {
      ph[i] = hb[2*i] | (hb[2*i+1] << 16);
      pl[i] = lb[2*i] | (lb[2*i+1] << 16);
    }
    *reinterpret_cast<u32x4*>(ws + WS_WH + mk * 1024 + L * 16) = ph;
    *reinterpret_cast<u32x4*>(ws + WS_WL + mk * 1024 + L * 16) = pl;
  }
}

// ---------------- Kernel 1: Gumbel-max sampling (unchanged R6) -------------
__global__ __launch_bounds__(1024)
void sample_kernel(const float* __restrict__ adj, int* __restrict__ sampled) {
  const int n = blockIdx.x;
  const int tid = threadIdx.x;
  const float la = logf(adj[(size_t)n * N_NODES + tid]);

  float best[K_NEIGH];
  int   bestj[K_NEIGH];
  #pragma unroll
  for (int k = 0; k < K_NEIGH; ++k) {
    uint32_t bits = threefry_bits(0u, (uint32_t)((n * K_NEIGH + k) * N_NODES + tid));
    best[k] = la + gumbel_from_bits(bits);
    bestj[k] = tid;
  }
  #pragma unroll
  for (int k = 0; k < K_NEIGH; ++k) {
    #pragma unroll
    for (int off = 32; off > 0; off >>= 1) {
      float ov = __shfl_down(best[k], off);
      int   oj = __shfl_down(bestj[k], off);
      if (ov > best[k] || (ov == best[k] && oj < bestj[k])) { best[k] = ov; bestj[k] = oj; }
    }
  }
  __shared__ float sv[16][K_NEIGH];
  __shared__ int   sj[16][K_NEIGH];
  if ((tid & 63) == 0) {
    #pragma unroll
    for (int k = 0; k < K_NEIGH; ++k) { sv[tid >> 6][k] = best[k]; sj[tid >> 6][k] = bestj[k]; }
  }
  __syncthreads();
  if (tid < K_NEIGH) {
    float b = sv[0][tid];
    int  bj = sj[0][tid];
    #pragma unroll
    for (int w = 1; w < 16; ++w) {
      if (sv[w][tid] > b || (sv[w][tid] == b && sj[w][tid] < bj)) { b = sv[w][tid]; bj = sj[w][tid]; }
    }
    sampled[n * K_NEIGH + tid] = bj;
  }
}

// 6-way uniform-pointer select by per-lane index (avoids runtime-indexed
// array -> scratch, rule #20). Emits a v_cndmask chain.
__device__ __forceinline__ const float* sel_row(const float* r0, const float* r1,
                                                const float* r2, const float* r3,
                                                const float* r4, const float* r5,
                                                int c) {
  const float* p = r0;
  p = (c == 1) ? r1 : p;
  p = (c == 2) ? r2 : p;
  p = (c == 3) ? r3 : p;
  p = (c == 4) ? r4 : p;
  p = (c == 5) ? r5 : p;
  return p;
}

// ---------------- Kernel 2: barrier-free direct-load MFMA embed ------------
// R8 post-mortem: LDS stage + 2 barriers/half at 2 waves/SIMD serialized the
// pipeline (~160 us). Here each lane loads ITS OWN B-frag straight from
// global: 8 consecutive k of one patch = two aligned float4 (L2-hot,
// 48 KB/bn), packs hi/lo in registers, MFMAs immediately. No LDS, no
// __syncthreads anywhere. Numerics/k-map/C-D map identical to verified R8.
// Bias folded into acc init. Nontemporal stores (write-once output).
__global__ __launch_bounds__(256)
void embed_kernel(const float* __restrict__ hist, const char* __restrict__ ws,
                  const float* __restrict__ bias, const int* __restrict__ sampled,
                  float* __restrict__ out) {
  const int tid  = threadIdx.x;
  const int L    = tid & 63;
  const int wave = tid >> 6;
  const int g    = L >> 4;          // 16-lane group = k-octet within kc
  const int col  = L & 15;          // patch within tile

  // persistent W-frags: wh/wl[m*3+kc] (verified R8 layout)
  bf16x8 wh[18], wl[18];
  #pragma unroll
  for (int mk = 0; mk < 18; ++mk) {
    wh[mk] = __builtin_bit_cast(bf16x8, *reinterpret_cast<const u32x4*>(ws + WS_WH + mk*1024 + L*16));
    wl[mk] = __builtin_bit_cast(bf16x8, *reinterpret_cast<const u32x4*>(ws + WS_WL + mk*1024 + L*16));
  }
  // bias for the 24 C/D rows this lane owns (acc init value)
  f32x4 bv[6];
  #pragma unroll
  for (int m = 0; m < 6; ++m)
    #pragma unroll
    for (int i = 0; i < 4; ++i)
      bv[m][i] = bias[m * 16 + g * 4 + i];

  for (int bn = blockIdx.x; bn < 4 * N_NODES; bn += 512) {
    const int n = bn & (N_NODES - 1);
    const int b = bn >> 10;
    const float* r0 = hist + (size_t)bn * L_TIME;
    const float* r1 = hist + ((size_t)b * N_NODES + sampled[n * K_NEIGH + 0]) * L_TIME;
    const float* r2 = hist + ((size_t)b * N_NODES + sampled[n * K_NEIGH + 1]) * L_TIME;
    const float* r3 = hist + ((size_t)b * N_NODES + sampled[n * K_NEIGH + 2]) * L_TIME;
    const float* r4 = hist + ((size_t)b * N_NODES + sampled[n * K_NEIGH + 3]) * L_TIME;
    const float* r5 = hist + ((size_t)b * N_NODES + sampled[n * K_NEIGH + 4]) * L_TIME;
    float* outbn = out + (size_t)bn * OUT_PER_BN;

    // per-lane source pointers for each kc: k-octet gk = kc*32 + g*8 spans
    // rows c0 (t0) and c1 (t1), all float4-aligned (t in {0,4,8}).
    const float* a0[3];
    const float* a1[3];
    bool okk[3];
    #pragma unroll
    for (int kc = 0; kc < 3; ++kc) {
      const int gk = kc * 32 + g * 8;
      okk[kc] = (gk < KDOT);
      const int c0 = gk / 12,       t0 = gk - c0 * 12;
      const int c1 = (gk + 4) / 12, t1 = (gk + 4) - c1 * 12;
      a0[kc] = sel_row(r0, r1, r2, r3, r4, r5, c0) + t0;
      a1[kc] = sel_row(r0, r1, r2, r3, r4, r5, c1) + t1;
    }

    for (int ntl = wave; ntl < 11; ntl += 4) {   // 11 patch-tiles, 4 waves
      const int p = ntl * 16 + col;              // 0..175
      const bool pok = (p < P_CNT);
      f32x4 acc[6];
      #pragma unroll
      for (int m = 0; m < 6; ++m) acc[m] = bv[m];

      #pragma unroll
      for (int kc = 0; kc < 3; ++kc) {
        u32x4 ph = {0,0,0,0}, pl = {0,0,0,0};
        if (okk[kc] && pok) {
          const float4 f0 = *reinterpret_cast<const float4*>(a0[kc] + p * PATCHSZ);
          const float4 f1 = *reinterpret_cast<const float4*>(a1[kc] + p * PATCHSZ);
          const float v[8] = {f0.x, f0.y, f0.z, f0.w, f1.x, f1.y, f1.z, f1.w};
          uint32_t hb[8], lb[8];
          #pragma unroll
          for (int j = 0; j < 8; ++j) {
            hb[j] = f2bf_bits(v[j]);
            lb[j] = f2bf_bits(v[j] - bf_hi_f(hb[j]));
          }
          #pragma unroll
          for (int i = 0; i < 4; ++i) {
            ph[i] = hb[2*i] | (hb[2*i+1] << 16);
            pl[i] = lb[2*i] | (lb[2*i+1] << 16);
          }
        }
        const bf16x8 xh = __builtin_bit_cast(bf16x8, ph);
        const bf16x8 xl = __builtin_bit_cast(bf16x8, pl);
        #pragma unroll
        for (int m = 0; m < 6; ++m) {
          acc[m] = __builtin_amdgcn_mfma_f32_16x16x32_bf16(wh[m*3+kc], xh, acc[m], 0, 0, 0);
          acc[m] = __builtin_amdgcn_mfma_f32_16x16x32_bf16(wh[m*3+kc], xl, acc[m], 0, 0, 0);
          acc[m] = __builtin_amdgcn_mfma_f32_16x16x32_bf16(wl[m*3+kc], xh, acc[m], 0, 0, 0);
        }
      }
      if (pok) {
        #pragma unroll
        for (int m = 0; m < 6; ++m) {
          const int o = m * 16 + g * 4;
          #pragma unroll
          for (int i = 0; i < 4; ++i)
            __builtin_nontemporal_store(acc[m][i], &outbn[(size_t)(o + i) * P_CNT + p]);
        }
      }
    }
  }
}

// ---------------- launch ----------------
extern "C" void kernel_launch(void* const* d_in, const int* in_sizes, int n_in,
                              void* d_out, int out_size, void* d_ws, size_t ws_size,
                              hipStream_t stream) {
  const float* hist = (const float*)d_in[0];  // [4,1024,1,2016]
  const float* adj  = (const float*)d_in[1];  // [1024,1024]
  const float* wgt  = (const float*)d_in[2];  // [96,6,12]
  const float* bias = (const float*)d_in[3];  // [96]
  float* out = (float*)d_out;                 // [4,1024,96,168]
  char* ws   = (char*)d_ws;                   // sampled @0, W-frags @24576
  int* sampled = (int*)d_ws;

  wpack_kernel<<<dim3(1), dim3(256), 0, stream>>>(wgt, ws);
  sample_kernel<<<dim3(N_NODES), dim3(1024), 0, stream>>>(adj, sampled);
  embed_kernel<<<dim3(512), dim3(256), 0, stream>>>(hist, ws, bias, sampled, out);
}